// Round 15
// baseline (245.710 us; speedup 1.0000x reference)
//
#include <hip/hip_runtime.h>
#include <hip/hip_bf16.h>
#include <stdint.h>

using bf16x8 = __attribute__((ext_vector_type(8))) __bf16;
using f32x4  = __attribute__((ext_vector_type(4))) float;
using i32x4  = __attribute__((ext_vector_type(4))) int;

#define GBM 256
#define GBN 256
#define GBK 64
#define GTHR 512   // 8 waves: 2(M) x 4(N); wave tile 128x64, acc 8x4
#define KS   8
#define PROWS 8

__device__ __forceinline__ void gload_lds16(const void* g, void* l) {
  __builtin_amdgcn_global_load_lds((const __attribute__((address_space(1))) void*)g,
                                   (__attribute__((address_space(3))) void*)l,
                                   16, 0, 0);
}

// ---- pack B (row-streaming, R9-proven, unchanged): 8 whole rows/block ----
// Panel p = 128 cols; tile t = [128 rows][8 slots];
// unit(row,sl) holds W[row][(sl^(row&7))*8 + t*64 ..+8]
__global__ __launch_bounds__(256)
void pack_rows(const int* __restrict__ qw, const float* __restrict__ scales,
               __bf16* __restrict__ wsB, int K, int NG, int nT) {
  const int tid = threadIdx.x;
  const int rloc = tid >> 5;
  const int ubase = tid & 31;
  const int n = blockIdx.x * PROWS + rloc;
  const int p = n >> 7;
  const int rit = n & 127;
  const int rb7 = rit & 7;
  const float* srow = scales + (size_t)n * NG;
  const int* qrow = qw + (size_t)n * K;
  __bf16* base = wsB + (size_t)p * nT * (128 * GBK) + (size_t)rit * GBK;

#pragma unroll
  for (int j = 0; j < 16; ++j) {
    const int cu = ubase + j * 32;           // k-unit 0..511
    const i32x4* src = reinterpret_cast<const i32x4*>(qrow + cu * 8);
    i32x4 q0 = src[0], q1 = src[1];
    const float s = srow[cu >> 4];           // GS=128 => 16 units/group
    const int t  = cu >> 3;                  // 8 units per 64-k tile
    const int sl = (cu & 7) ^ rb7;
    bf16x8 w;
    w[0] = (__bf16)((float)q0[0] * s); w[1] = (__bf16)((float)q0[1] * s);
    w[2] = (__bf16)((float)q0[2] * s); w[3] = (__bf16)((float)q0[3] * s);
    w[4] = (__bf16)((float)q1[0] * s); w[5] = (__bf16)((float)q1[1] * s);
    w[6] = (__bf16)((float)q1[2] * s); w[7] = (__bf16)((float)q1[3] * s);
    *reinterpret_cast<bf16x8*>(base + (size_t)t * (128 * GBK) + sl * 8) = w;
  }
}

// ---- pack A (R9-proven, unchanged): x fp32 -> bf16, 128-row bands ----
__global__ __launch_bounds__(256)
void xcvt_p(const float* __restrict__ x, __bf16* __restrict__ wsA, int K, int nT) {
  const int U  = blockIdx.x * 256 + threadIdx.x;
  const int uu = U & 1023;
  const int tt = (U >> 10) % nT;
  const int bb = (U >> 10) / nT;             // 128-row band
  const int row = uu >> 3, slot = uu & 7;
  const int c8 = slot ^ (row & 7);
  const f32x4* src = reinterpret_cast<const f32x4*>(
      x + (size_t)(bb * 128 + row) * K + tt * GBK + c8 * 8);
  f32x4 a = src[0], b = src[1];
  bf16x8 w;
  w[0] = (__bf16)a[0]; w[1] = (__bf16)a[1]; w[2] = (__bf16)a[2]; w[3] = (__bf16)a[3];
  w[4] = (__bf16)b[0]; w[5] = (__bf16)b[1]; w[6] = (__bf16)b[2]; w[7] = (__bf16)b[3];
  *reinterpret_cast<bf16x8*>(wsA + (size_t)U * 8) = w;
}

// ---- out = bias (broadcast), rewritten every replay (R11-proven) ----
__global__ __launch_bounds__(256)
void bias_init(const float* __restrict__ bias, float* __restrict__ out, int N) {
  const size_t i = ((size_t)blockIdx.x * 256 + threadIdx.x) * 4;
  const int n = (int)(i % N);
  f32x4 b = *reinterpret_cast<const f32x4*>(bias + n);
  *reinterpret_cast<f32x4*>(out + i) = b;
}

// ---- packed GEMM: 256x256 tile, K-split x8, atomic epilogue ----
__global__ __launch_bounds__(GTHR, 2)
void gemm_packed(const __bf16* __restrict__ wsA, const __bf16* __restrict__ wsB,
                 float* __restrict__ out, int N, int K, int gx) {
  __shared__ __bf16 As[2][GBM * GBK];   // 2 x 32 KiB (bands stacked at 0 / 8192)
  __shared__ __bf16 Bs[2][GBN * GBK];   // 2 x 32 KiB (panels stacked at 0 / 8192)

  const int tid  = threadIdx.x;
  const int lane = tid & 63;
  const int wv   = tid >> 6;            // 0..7
  const int wr   = wv >> 2;             // 0..1 (M): rows wr*128 ..
  const int wc   = wv & 3;              // 0..3 (N): cols wc*64 ..

  // XCD chunk (688 = 8*86 exact): contiguous wgids per XCD.
  int wgid = blockIdx.x;
  if ((gridDim.x & 7) == 0) {
    const int q = gridDim.x >> 3;
    wgid = (blockIdx.x & 7) * q + (blockIdx.x >> 3);
  }
  // by,ks innermost: the 16 sharers of one B panel-pair are consecutive
  const int bx  = wgid / (2 * KS);
  const int rem = wgid % (2 * KS);
  const int by  = rem / KS;
  const int ks  = rem % KS;

  const int l15 = lane & 15;
  const int l4  = lane >> 4;
  const int nTfull = K / GBK;           // 64
  const int nT  = nTfull / KS;          // 8
  const int tBase = ks * nT;

  const size_t bandStride = (size_t)nTfull * (128 * GBK);
  const __bf16* a0base = wsA + (size_t)(2 * by)     * bandStride;
  const __bf16* a1base = wsA + (size_t)(2 * by + 1) * bandStride;
  const __bf16* b0base = wsB + (size_t)(2 * bx)     * bandStride;
  const __bf16* b1base = wsB + (size_t)(2 * bx + 1) * bandStride;

  f32x4 acc[8][4];
#pragma unroll
  for (int m = 0; m < 8; ++m)
#pragma unroll
    for (int n = 0; n < 4; ++n) acc[m][n] = (f32x4)0.0f;

  // 8 gload_lds16 per thread per stage (A band0/1 x2, B panel0/1 x2)
  auto STAGE = [&](int buf, int t) {
    const __bf16* a0 = a0base + (size_t)t * (128 * GBK);
    const __bf16* a1 = a1base + (size_t)t * (128 * GBK);
    const __bf16* b0 = b0base + (size_t)t * (128 * GBK);
    const __bf16* b1 = b1base + (size_t)t * (128 * GBK);
#pragma unroll
    for (int i = 0; i < 2; ++i) {
      const int ub = (i * 8 + wv) * 64;               // units 0..1023 per band
      gload_lds16(a0 + (size_t)(ub + lane) * 8, &As[buf][ub * 8]);
      gload_lds16(a1 + (size_t)(ub + lane) * 8, &As[buf][8192 + ub * 8]);
      gload_lds16(b0 + (size_t)(ub + lane) * 8, &Bs[buf][ub * 8]);
      gload_lds16(b1 + (size_t)(ub + lane) * 8, &Bs[buf][8192 + ub * 8]);
    }
  };

  auto MF = [&](const __bf16* A_, const __bf16* B_) {
#pragma unroll
    for (int kk = 0; kk < 2; ++kk) {
      const int c8 = kk * 4 + l4;
      bf16x8 af[8], bf_[4];
#pragma unroll
      for (int m = 0; m < 8; ++m) {
        const int row = wr * 128 + m * 16 + l15;      // 0..255
        const int slot = c8 ^ (row & 7);
        af[m] = *reinterpret_cast<const bf16x8*>(&A_[row * GBK + slot * 8]);
      }
#pragma unroll
      for (int n = 0; n < 4; ++n) {
        const int col = wc * 64 + n * 16 + l15;       // 0..255
        const int slot = c8 ^ (col & 7);
        bf_[n] = *reinterpret_cast<const bf16x8*>(&B_[col * GBK + slot * 8]);
      }
#pragma unroll
      for (int m = 0; m < 8; ++m)
#pragma unroll
        for (int n = 0; n < 4; ++n)
          acc[m][n] = __builtin_amdgcn_mfma_f32_16x16x32_bf16(af[m], bf_[n], acc[m][n], 0, 0, 0);
    }
  };

  STAGE(0, tBase + 0);
  STAGE(1, tBase + 1);                   // 16 VMEM outstanding per thread

  int cur = 0;
  for (int t = 0; t < nT; ++t) {
    if (t + 1 < nT) { asm volatile("s_waitcnt vmcnt(8)" ::: "memory"); }
    else            { asm volatile("s_waitcnt vmcnt(0)" ::: "memory"); }
    __builtin_amdgcn_s_barrier();
    __builtin_amdgcn_sched_barrier(0);
    MF(As[cur], Bs[cur]);
    __builtin_amdgcn_sched_barrier(0);
    __builtin_amdgcn_s_barrier();
    if (t + 2 < nT) STAGE(cur, tBase + t + 2);
    __builtin_amdgcn_sched_barrier(0);
    cur ^= 1;
  }

  // atomic epilogue: out pre-initialized to bias; KS partials per element
  const int tileM = by * GBM, tileN = bx * GBN;
#pragma unroll
  for (int n = 0; n < 4; ++n) {
    const int col = tileN + wc * 64 + n * 16 + l15;
#pragma unroll
    for (int m = 0; m < 8; ++m) {
      const int rbase = tileM + wr * 128 + m * 16 + l4 * 4;
#pragma unroll
      for (int r = 0; r < 4; ++r)
        atomicAdd(&out[(size_t)(rbase + r) * N + col], acc[m][n][r]);
    }
  }
}

// ======================= last-resort fallback (no ws) =======================
#define FBM 128
#define FBN 128
#define FBK 64
__global__ __launch_bounds__(256)
void gptq_gemm_fb(const float* __restrict__ x, const int* __restrict__ qw,
                  const float* __restrict__ scales, const float* __restrict__ bias,
                  float* __restrict__ out, int M, int N, int K, int NG, int GS) {
  __shared__ __bf16 lds_a[FBM * FBK];
  __shared__ __bf16 lds_b[FBN * FBK];
  const int tid = threadIdx.x, lane = tid & 63, wave = tid >> 6;
  const int wr = wave >> 1, wc = wave & 1;
  const int tileM = blockIdx.y * FBM, tileN = blockIdx.x * FBN;
  const int l15 = lane & 15, l4 = lane >> 4;
  f32x4 acc[4][4];
#pragma unroll
  for (int m = 0; m < 4; ++m)
#pragma unroll
    for (int n = 0; n < 4; ++n) acc[m][n] = (f32x4)0.0f;
  for (int k0 = 0; k0 < K; k0 += FBK) {
    const int g = k0 / GS;
#pragma unroll
    for (int i = 0; i < 4; ++i) {
      int u = i * 256 + tid, row = u >> 3, c8 = u & 7;
      const f32x4* src = reinterpret_cast<const f32x4*>(x + (size_t)(tileM + row) * K + k0 + c8 * 8);
      f32x4 v0 = src[0], v1 = src[1];
      bf16x8 w;
      w[0]=(__bf16)v0[0]; w[1]=(__bf16)v0[1]; w[2]=(__bf16)v0[2]; w[3]=(__bf16)v0[3];
      w[4]=(__bf16)v1[0]; w[5]=(__bf16)v1[1]; w[6]=(__bf16)v1[2]; w[7]=(__bf16)v1[3];
      int slot = c8 ^ (row & 7);
      *reinterpret_cast<bf16x8*>(&lds_a[row * FBK + slot * 8]) = w;
    }
#pragma unroll
    for (int i = 0; i < 4; ++i) {
      int u = i * 256 + tid, row = u >> 3, c8 = u & 7;
      int gn = tileN + row;
      const i32x4* src = reinterpret_cast<const i32x4*>(qw + (size_t)gn * K + k0 + c8 * 8);
      i32x4 q0 = src[0], q1 = src[1];
      float s = scales[gn * NG + g];
      bf16x8 w;
      w[0]=(__bf16)((float)q0[0]*s); w[1]=(__bf16)((float)q0[1]*s);
      w[2]=(__bf16)((float)q0[2]*s); w[3]=(__bf16)((float)q0[3]*s);
      w[4]=(__bf16)((float)q1[0]*s); w[5]=(__bf16)((float)q1[1]*s);
      w[6]=(__bf16)((float)q1[2]*s); w[7]=(__bf16)((float)q1[3]*s);
      int slot = c8 ^ (row & 7);
      *reinterpret_cast<bf16x8*>(&lds_b[row * FBK + slot * 8]) = w;
    }
    __syncthreads();
#pragma unroll
    for (int kk = 0; kk < FBK; kk += 32) {
      bf16x8 af[4], bfr[4];
#pragma unroll
      for (int m = 0; m < 4; ++m) {
        int row = wr * 64 + m * 16 + l15, slot = ((kk >> 3) + l4) ^ (row & 7);
        af[m] = *reinterpret_cast<const bf16x8*>(&lds_a[row * FBK + slot * 8]);
      }
#pragma unroll
      for (int n = 0; n < 4; ++n) {
        int row = wc * 64 + n * 16 + l15, slot = ((kk >> 3) + l4) ^ (row & 7);
        bfr[n] = *reinterpret_cast<const bf16x8*>(&lds_b[row * FBK + slot * 8]);
      }
#pragma unroll
      for (int m = 0; m < 4; ++m)
#pragma unroll
        for (int n = 0; n < 4; ++n)
          acc[m][n] = __builtin_amdgcn_mfma_f32_16x16x32_bf16(af[m], bfr[n], acc[m][n], 0, 0, 0);
    }
    __syncthreads();
  }
#pragma unroll
  for (int n = 0; n < 4; ++n) {
    int coln = tileN + wc * 64 + n * 16 + l15;
    float bv = bias[coln];
#pragma unroll
    for (int m = 0; m < 4; ++m) {
      int rbase = tileM + wr * 64 + m * 16 + l4 * 4;
#pragma unroll
      for (int r = 0; r < 4; ++r)
        out[(size_t)(rbase + r) * N + coln] = acc[m][n][r] + bv;
    }
  }
}

extern "C" void kernel_launch(void* const* d_in, const int* in_sizes, int n_in,
                              void* d_out, int out_size, void* d_ws, size_t ws_size,
                              hipStream_t stream) {
  const float* x      = (const float*)d_in[0];
  const int*   qw     = (const int*)d_in[1];
  const float* scales = (const float*)d_in[2];
  const float* bias   = (const float*)d_in[3];
  float*       out    = (float*)d_out;

  const int OUT = in_sizes[3];            // 11008
  const int IN  = in_sizes[1] / OUT;      // 4096
  const int M   = in_sizes[0] / IN;       // 512
  const int NG  = in_sizes[2] / OUT;      // 32
  const int GS  = IN / NG;                // 128

  const size_t needB = (size_t)OUT * IN * sizeof(__bf16);   // 90.2 MB
  const size_t needA = (size_t)M * IN * sizeof(__bf16);     // 4.2 MB
  const int nT = IN / GBK;                                  // 64

  const bool ok_packed =
      (ws_size >= needB + needA) && (M % GBM == 0) && (OUT % GBN == 0) &&
      (nT % (2 * KS) == 0) && (GS == 128) && (NG == IN / 128) &&
      (OUT % PROWS == 0) && ((M * OUT) % 1024 == 0) && (OUT % 4 == 0);

  if (ok_packed) {
    __bf16* wsB = (__bf16*)d_ws;
    __bf16* wsA = (__bf16*)((char*)d_ws + needB);
    pack_rows<<<OUT / PROWS, 256, 0, stream>>>(qw, scales, wsB, IN, NG, nT);
    const int bands = M / 128;            // 4
    const int unitsA = bands * nT * 1024;
    xcvt_p<<<unitsA / 256, 256, 0, stream>>>(x, wsA, IN, nT);
    bias_init<<<(M * OUT) / 1024, 256, 0, stream>>>(bias, out, OUT);
    const int gx = OUT / GBN;             // 43
    const int gy = M / GBM;               // 2
    gemm_packed<<<gx * gy * KS, GTHR, 0, stream>>>(wsA, wsB, out, OUT, IN, gx);
  } else {
    dim3 grid(OUT / FBN, M / FBM);
    gptq_gemm_fb<<<grid, 256, 0, stream>>>(x, qw, scales, bias, out, M, OUT, IN, NG, GS);
  }
}

// Round 16
// 201.239 us; speedup vs baseline: 1.2210x; 1.2210x over previous
//
#include <hip/hip_runtime.h>
#include <hip/hip_bf16.h>
#include <stdint.h>

using bf16x8 = __attribute__((ext_vector_type(8))) __bf16;
using f32x4  = __attribute__((ext_vector_type(4))) float;
using i32x4  = __attribute__((ext_vector_type(4))) int;

#define GBM 256
#define GBN 256
#define GBK 32
#define GTHR 512   // 8 waves: 2(M) x 4(N); wave tile 128x64, acc 8x4
#define KS   4
#define PROWS 8

__device__ __forceinline__ void gload_lds16(const void* g, void* l) {
  __builtin_amdgcn_global_load_lds((const __attribute__((address_space(1))) void*)g,
                                   (__attribute__((address_space(3))) void*)l,
                                   16, 0, 0);
}

// ---- pack B (R10-proven GBK=32): 8 whole rows/block, sequential reads ----
// Panel p = 128 cols; tile t = [128 rows][4 slots];
// unit(row,sl) holds W[row][(sl^(row&3))*8 + t*32 ..+8]
__global__ __launch_bounds__(256)
void pack_rows(const int* __restrict__ qw, const float* __restrict__ scales,
               __bf16* __restrict__ wsB, int K, int NG, int nT) {
  const int tid = threadIdx.x;
  const int rloc = tid >> 5;
  const int ubase = tid & 31;
  const int n = blockIdx.x * PROWS + rloc;
  const int p = n >> 7;
  const int rit = n & 127;
  const int rb3 = rit & 3;
  const float* srow = scales + (size_t)n * NG;
  const int* qrow = qw + (size_t)n * K;
  __bf16* base = wsB + (size_t)p * nT * (128 * GBK) + (size_t)rit * GBK;

#pragma unroll
  for (int j = 0; j < 16; ++j) {
    const int cu = ubase + j * 32;           // k-unit 0..511
    const i32x4* src = reinterpret_cast<const i32x4*>(qrow + cu * 8);
    i32x4 q0 = src[0], q1 = src[1];
    const float s = srow[cu >> 4];           // GS=128 => 16 units/group
    const int t  = cu >> 2;                  // 4 units per 32-k tile
    const int sl = (cu & 3) ^ rb3;
    bf16x8 w;
    w[0] = (__bf16)((float)q0[0] * s); w[1] = (__bf16)((float)q0[1] * s);
    w[2] = (__bf16)((float)q0[2] * s); w[3] = (__bf16)((float)q0[3] * s);
    w[4] = (__bf16)((float)q1[0] * s); w[5] = (__bf16)((float)q1[1] * s);
    w[6] = (__bf16)((float)q1[2] * s); w[7] = (__bf16)((float)q1[3] * s);
    *reinterpret_cast<bf16x8*>(base + (size_t)t * (128 * GBK) + sl * 8) = w;
  }
}

// ---- pack A (R10-proven GBK=32): x fp32 -> bf16, 128-row bands ----
__global__ __launch_bounds__(256)
void xcvt_p(const float* __restrict__ x, __bf16* __restrict__ wsA, int K, int nT) {
  const int U  = blockIdx.x * 256 + threadIdx.x;
  const int uu = U & 511;                    // 512 units per tile
  const int tt = (U >> 9) % nT;
  const int bb = (U >> 9) / nT;              // 128-row band
  const int row = uu >> 2, slot = uu & 3;
  const int c = slot ^ (row & 3);
  const f32x4* src = reinterpret_cast<const f32x4*>(
      x + (size_t)(bb * 128 + row) * K + tt * GBK + c * 8);
  f32x4 a = src[0], b = src[1];
  bf16x8 w;
  w[0] = (__bf16)a[0]; w[1] = (__bf16)a[1]; w[2] = (__bf16)a[2]; w[3] = (__bf16)a[3];
  w[4] = (__bf16)b[0]; w[5] = (__bf16)b[1]; w[6] = (__bf16)b[2]; w[7] = (__bf16)b[3];
  *reinterpret_cast<bf16x8*>(wsA + (size_t)U * 8) = w;
}

// ---- out = bias (broadcast), rewritten every replay (R11-proven) ----
__global__ __launch_bounds__(256)
void bias_init(const float* __restrict__ bias, float* __restrict__ out, int N) {
  const size_t i = ((size_t)blockIdx.x * 256 + threadIdx.x) * 4;
  const int n = (int)(i % N);
  f32x4 b = *reinterpret_cast<const f32x4*>(bias + n);
  *reinterpret_cast<f32x4*>(out + i) = b;
}

// ---- packed GEMM: 256x256 tile, GBK=32, KS=4, 64KB LDS (2 blocks/CU) ----
__global__ __launch_bounds__(GTHR, 2)
void gemm_packed(const __bf16* __restrict__ wsA, const __bf16* __restrict__ wsB,
                 float* __restrict__ out, int N, int K, int gy) {
  __shared__ __bf16 As[2][GBM * GBK];   // 2 x 16 KiB (bands at 0 / 4096)
  __shared__ __bf16 Bs[2][GBN * GBK];   // 2 x 16 KiB (panels at 0 / 4096)

  const int tid  = threadIdx.x;
  const int lane = tid & 63;
  const int wv   = tid >> 6;            // 0..7
  const int wr   = wv >> 2;             // 0..1 (M): rows wr*128 ..
  const int wc   = wv & 3;              // 0..3 (N): cols wc*64 ..

  // XCD chunk (344 = 8*43 exact): contiguous wgids per XCD.
  int wgid = blockIdx.x;
  if ((gridDim.x & 7) == 0) {
    const int q = gridDim.x >> 3;
    wgid = (blockIdx.x & 7) * q + (blockIdx.x >> 3);
  }
  // by innermost: the 2 sharers of one B slab (bx,ks) are consecutive -> same XCD
  const int bx  = wgid / (gy * KS);
  const int rem = wgid % (gy * KS);
  const int ks  = rem / gy;
  const int by  = rem % gy;

  const int l15 = lane & 15;
  const int l4  = lane >> 4;
  const int nTfull = K / GBK;           // 128
  const int nT  = nTfull / KS;          // 32 steps per block
  const int tBase = ks * nT;

  const size_t bandStride = (size_t)nTfull * (128 * GBK);   // 524288 elems
  const __bf16* a0base = wsA + (size_t)(2 * by)     * bandStride;
  const __bf16* a1base = wsA + (size_t)(2 * by + 1) * bandStride;
  const __bf16* b0base = wsB + (size_t)(2 * bx)     * bandStride;
  const __bf16* b1base = wsB + (size_t)(2 * bx + 1) * bandStride;

  f32x4 acc[8][4];
#pragma unroll
  for (int m = 0; m < 8; ++m)
#pragma unroll
    for (int n = 0; n < 4; ++n) acc[m][n] = (f32x4)0.0f;

  // 4 gload_lds16 per thread per stage (A band0/1, B panel0/1; 512 units each)
  auto STAGE = [&](int buf, int t) {
    const __bf16* a0 = a0base + (size_t)t * 4096;
    const __bf16* a1 = a1base + (size_t)t * 4096;
    const __bf16* b0 = b0base + (size_t)t * 4096;
    const __bf16* b1 = b1base + (size_t)t * 4096;
    const int u = wv * 64 + lane;       // unit 0..511
    gload_lds16(a0 + (size_t)u * 8, &As[buf][wv * 512]);
    gload_lds16(a1 + (size_t)u * 8, &As[buf][4096 + wv * 512]);
    gload_lds16(b0 + (size_t)u * 8, &Bs[buf][wv * 512]);
    gload_lds16(b1 + (size_t)u * 8, &Bs[buf][4096 + wv * 512]);
  };

  auto MF = [&](const __bf16* A_, const __bf16* B_) {
    bf16x8 af[8], bf_[4];
#pragma unroll
    for (int m = 0; m < 8; ++m) {
      const int row = wr * 128 + m * 16 + l15;      // 0..255 (band1 at 4096)
      const int sl = l4 ^ (row & 3);
      af[m] = *reinterpret_cast<const bf16x8*>(&A_[row * GBK + sl * 8]);
    }
#pragma unroll
    for (int n = 0; n < 4; ++n) {
      const int col = wc * 64 + n * 16 + l15;       // 0..255
      const int sl = l4 ^ (col & 3);
      bf_[n] = *reinterpret_cast<const bf16x8*>(&B_[col * GBK + sl * 8]);
    }
#pragma unroll
    for (int m = 0; m < 8; ++m)
#pragma unroll
      for (int n = 0; n < 4; ++n)
        acc[m][n] = __builtin_amdgcn_mfma_f32_16x16x32_bf16(af[m], bf_[n], acc[m][n], 0, 0, 0);
  };

  STAGE(0, tBase + 0);
  STAGE(1, tBase + 1);                   // 8 VMEM outstanding per thread

  int cur = 0;
  for (int t = 0; t < nT; ++t) {
    if (t + 1 < nT) { asm volatile("s_waitcnt vmcnt(4)" ::: "memory"); }
    else            { asm volatile("s_waitcnt vmcnt(0)" ::: "memory"); }
    __builtin_amdgcn_s_barrier();
    __builtin_amdgcn_sched_barrier(0);
    MF(As[cur], Bs[cur]);
    __builtin_amdgcn_sched_barrier(0);
    __builtin_amdgcn_s_barrier();
    if (t + 2 < nT) STAGE(cur, tBase + t + 2);
    __builtin_amdgcn_sched_barrier(0);
    cur ^= 1;
  }

  // atomic epilogue: out pre-initialized to bias; KS partials per element
  const int tileM = by * GBM, tileN = bx * GBN;
#pragma unroll
  for (int n = 0; n < 4; ++n) {
    const int col = tileN + wc * 64 + n * 16 + l15;
#pragma unroll
    for (int m = 0; m < 8; ++m) {
      const int rbase = tileM + wr * 128 + m * 16 + l4 * 4;
#pragma unroll
      for (int r = 0; r < 4; ++r)
        atomicAdd(&out[(size_t)(rbase + r) * N + col], acc[m][n][r]);
    }
  }
}

// ======================= last-resort fallback (no ws) =======================
#define FBM 128
#define FBN 128
#define FBK 64
__global__ __launch_bounds__(256)
void gptq_gemm_fb(const float* __restrict__ x, const int* __restrict__ qw,
                  const float* __restrict__ scales, const float* __restrict__ bias,
                  float* __restrict__ out, int M, int N, int K, int NG, int GS) {
  __shared__ __bf16 lds_a[FBM * FBK];
  __shared__ __bf16 lds_b[FBN * FBK];
  const int tid = threadIdx.x, lane = tid & 63, wave = tid >> 6;
  const int wr = wave >> 1, wc = wave & 1;
  const int tileM = blockIdx.y * FBM, tileN = blockIdx.x * FBN;
  const int l15 = lane & 15, l4 = lane >> 4;
  f32x4 acc[4][4];
#pragma unroll
  for (int m = 0; m < 4; ++m)
#pragma unroll
    for (int n = 0; n < 4; ++n) acc[m][n] = (f32x4)0.0f;
  for (int k0 = 0; k0 < K; k0 += FBK) {
    const int g = k0 / GS;
#pragma unroll
    for (int i = 0; i < 4; ++i) {
      int u = i * 256 + tid, row = u >> 3, c8 = u & 7;
      const f32x4* src = reinterpret_cast<const f32x4*>(x + (size_t)(tileM + row) * K + k0 + c8 * 8);
      f32x4 v0 = src[0], v1 = src[1];
      bf16x8 w;
      w[0]=(__bf16)v0[0]; w[1]=(__bf16)v0[1]; w[2]=(__bf16)v0[2]; w[3]=(__bf16)v0[3];
      w[4]=(__bf16)v1[0]; w[5]=(__bf16)v1[1]; w[6]=(__bf16)v1[2]; w[7]=(__bf16)v1[3];
      int slot = c8 ^ (row & 7);
      *reinterpret_cast<bf16x8*>(&lds_a[row * FBK + slot * 8]) = w;
    }
#pragma unroll
    for (int i = 0; i < 4; ++i) {
      int u = i * 256 + tid, row = u >> 3, c8 = u & 7;
      int gn = tileN + row;
      const i32x4* src = reinterpret_cast<const i32x4*>(qw + (size_t)gn * K + k0 + c8 * 8);
      i32x4 q0 = src[0], q1 = src[1];
      float s = scales[gn * NG + g];
      bf16x8 w;
      w[0]=(__bf16)((float)q0[0]*s); w[1]=(__bf16)((float)q0[1]*s);
      w[2]=(__bf16)((float)q0[2]*s); w[3]=(__bf16)((float)q0[3]*s);
      w[4]=(__bf16)((float)q1[0]*s); w[5]=(__bf16)((float)q1[1]*s);
      w[6]=(__bf16)((float)q1[2]*s); w[7]=(__bf16)((float)q1[3]*s);
      int slot = c8 ^ (row & 7);
      *reinterpret_cast<bf16x8*>(&lds_b[row * FBK + slot * 8]) = w;
    }
    __syncthreads();
#pragma unroll
    for (int kk = 0; kk < FBK; kk += 32) {
      bf16x8 af[4], bfr[4];
#pragma unroll
      for (int m = 0; m < 4; ++m) {
        int row = wr * 64 + m * 16 + l15, slot = ((kk >> 3) + l4) ^ (row & 7);
        af[m] = *reinterpret_cast<const bf16x8*>(&lds_a[row * FBK + slot * 8]);
      }
#pragma unroll
      for (int n = 0; n < 4; ++n) {
        int row = wc * 64 + n * 16 + l15, slot = ((kk >> 3) + l4) ^ (row & 7);
        bfr[n] = *reinterpret_cast<const bf16x8*>(&lds_b[row * FBK + slot * 8]);
      }
#pragma unroll
      for (int m = 0; m < 4; ++m)
#pragma unroll
        for (int n = 0; n < 4; ++n)
          acc[m][n] = __builtin_amdgcn_mfma_f32_16x16x32_bf16(af[m], bfr[n], acc[m][n], 0, 0, 0);
    }
    __syncthreads();
  }
#pragma unroll
  for (int n = 0; n < 4; ++n) {
    int coln = tileN + wc * 64 + n * 16 + l15;
    float bv = bias[coln];
#pragma unroll
    for (int m = 0; m < 4; ++m) {
      int rbase = tileM + wr * 64 + m * 16 + l4 * 4;
#pragma unroll
      for (int r = 0; r < 4; ++r)
        out[(size_t)(rbase + r) * N + coln] = acc[m][n][r] + bv;
    }
  }
}

extern "C" void kernel_launch(void* const* d_in, const int* in_sizes, int n_in,
                              void* d_out, int out_size, void* d_ws, size_t ws_size,
                              hipStream_t stream) {
  const float* x      = (const float*)d_in[0];
  const int*   qw     = (const int*)d_in[1];
  const float* scales = (const float*)d_in[2];
  const float* bias   = (const float*)d_in[3];
  float*       out    = (float*)d_out;

  const int OUT = in_sizes[3];            // 11008
  const int IN  = in_sizes[1] / OUT;      // 4096
  const int M   = in_sizes[0] / IN;       // 512
  const int NG  = in_sizes[2] / OUT;      // 32
  const int GS  = IN / NG;                // 128

  const size_t needB = (size_t)OUT * IN * sizeof(__bf16);   // 90.2 MB
  const size_t needA = (size_t)M * IN * sizeof(__bf16);     // 4.2 MB
  const int nT = IN / GBK;                                  // 128

  const bool ok_packed =
      (ws_size >= needB + needA) && (M % GBM == 0) && (OUT % GBN == 0) &&
      (IN % GBK == 0) && (nT % KS == 0) && ((nT / KS) >= 4) &&
      (GS == 128) && (NG == IN / 128) && (OUT % PROWS == 0) &&
      ((M * OUT) % 1024 == 0) && (OUT % 4 == 0);

  if (ok_packed) {
    __bf16* wsB = (__bf16*)d_ws;
    __bf16* wsA = (__bf16*)((char*)d_ws + needB);
    pack_rows<<<OUT / PROWS, 256, 0, stream>>>(qw, scales, wsB, IN, NG, nT);
    const int bands = M / 128;            // 4
    const int unitsA = bands * nT * 512;
    xcvt_p<<<unitsA / 256, 256, 0, stream>>>(x, wsA, IN, nT);
    bias_init<<<(M * OUT) / 1024, 256, 0, stream>>>(bias, out, OUT);
    const int gx = OUT / GBN;             // 43
    const int gy = M / GBM;               // 2
    gemm_packed<<<gx * gy * KS, GTHR, 0, stream>>>(wsA, wsB, out, OUT, IN, gy);
  } else {
    dim3 grid(OUT / FBN, M / FBM);
    gptq_gemm_fb<<<grid, 256, 0, stream>>>(x, qw, scales, bias, out, M, OUT, IN, NG, GS);
  }
}

// Round 17
// 87.332 us; speedup vs baseline: 2.8135x; 2.3043x over previous
//
#include <hip/hip_runtime.h>
#include <hip/hip_bf16.h>
#include <stdint.h>

using bf16x8 = __attribute__((ext_vector_type(8))) __bf16;
using f32x4  = __attribute__((ext_vector_type(4))) float;
using i32x4  = __attribute__((ext_vector_type(4))) int;

#define TM 128
#define TN 128
#define TK 128      // int8 K-tile: 128 rows x 128 k x 1B = 16 KB per operand
#define PROWS 8

__device__ __forceinline__ void gload_lds16(const void* g, void* l) {
  __builtin_amdgcn_global_load_lds((const __attribute__((address_space(1))) void*)g,
                                   (__attribute__((address_space(3))) void*)l,
                                   16, 0, 0);
}

__device__ __forceinline__ int pack4(int a, int b, int c, int d) {
  return (a & 0xFF) | ((b & 0xFF) << 8) | ((c & 0xFF) << 16) | ((d & 0xFF) << 24);
}

// ---- pack B: raw int8 q, row-streaming (sequential 64B reads per lane) ----
// wsB layout: [panel p (128 cols)][tile t (128 k)][row 0..127][slot 0..7]
// slot sl holds q[row][ (sl^(row&7))*16 + t*128 .. +16 ]  (16B units, XOR-swz)
__global__ __launch_bounds__(256)
void pack_rows_i8(const int* __restrict__ qw, int8_t* __restrict__ wsB,
                  int K, int nT) {
  const int tid = threadIdx.x;
  const int rloc = tid >> 5;                  // 0..7
  const int lane32 = tid & 31;
  const int n = blockIdx.x * PROWS + rloc;
  const int p = n >> 7;
  const int rit = n & 127;
  const int rb7 = rit & 7;
  const int* qrow = qw + (size_t)n * K;
  int8_t* base = wsB + (size_t)p * nT * 16384 + rit * 128;

#pragma unroll
  for (int j = 0; j < 8; ++j) {
    const int cu = lane32 + j * 32;           // 16-elem k-unit 0..255
    const i32x4* s4 = reinterpret_cast<const i32x4*>(qrow + cu * 16);
    i32x4 q0 = s4[0], q1 = s4[1], q2 = s4[2], q3 = s4[3];
    const int t  = cu >> 3;                   // 8 units per 128-k tile
    const int sl = (cu & 7) ^ rb7;
    i32x4 w;
    w[0] = pack4(q0[0], q0[1], q0[2], q0[3]);
    w[1] = pack4(q1[0], q1[1], q1[2], q1[3]);
    w[2] = pack4(q2[0], q2[1], q2[2], q2[3]);
    w[3] = pack4(q3[0], q3[1], q3[2], q3[3]);
    *reinterpret_cast<i32x4*>(base + (size_t)t * 16384 + sl * 16) = w;
  }
}

// ---- pack A: x fp32 -> int8 (scale 1/16), same [band][t][row][slot] layout ----
__global__ __launch_bounds__(256)
void xcvt_i8(const float* __restrict__ x, int8_t* __restrict__ wsA, int K, int nT) {
  const int U  = blockIdx.x * 256 + threadIdx.x;
  const int uu = U & 1023;
  const int tt = (U >> 10) % nT;
  const int bb = (U >> 10) / nT;              // 128-row band
  const int row = uu >> 3, sl = uu & 7;
  const int c16 = sl ^ (row & 7);
  const f32x4* src = reinterpret_cast<const f32x4*>(
      x + (size_t)(bb * 128 + row) * K + tt * TK + c16 * 16);
  f32x4 v0 = src[0], v1 = src[1], v2 = src[2], v3 = src[3];
  int q[16];
#pragma unroll
  for (int e = 0; e < 4; ++e) {
    q[e]      = __float2int_rn(v0[e] * 16.f);
    q[4 + e]  = __float2int_rn(v1[e] * 16.f);
    q[8 + e]  = __float2int_rn(v2[e] * 16.f);
    q[12 + e] = __float2int_rn(v3[e] * 16.f);
  }
#pragma unroll
  for (int e = 0; e < 16; ++e) q[e] = q[e] > 127 ? 127 : (q[e] < -127 ? -127 : q[e]);
  i32x4 w;
  w[0] = pack4(q[0], q[1], q[2], q[3]);
  w[1] = pack4(q[4], q[5], q[6], q[7]);
  w[2] = pack4(q[8], q[9], q[10], q[11]);
  w[3] = pack4(q[12], q[13], q[14], q[15]);
  *reinterpret_cast<i32x4*>(wsA + (size_t)U * 16) = w;
}

// ---- int8 GEMM: R9 step engine (128^2, 4 waves 2x2, vmcnt(8) 2-deep) ----
__global__ __launch_bounds__(256, 2)
void gemm_i8(const int8_t* __restrict__ wsA, const int8_t* __restrict__ wsB,
             const float* __restrict__ scales, const float* __restrict__ bias,
             float* __restrict__ out, int N, int K, int NG, int gy) {
  __shared__ int8_t As[2][16384];             // 2 x 16 KiB
  __shared__ int8_t Bs[2][16384];             // 2 x 16 KiB
  __shared__ float  sS[32 * 128];             // 16 KiB: [g][col], pre-scaled 1/16

  const int tid  = threadIdx.x;
  const int lane = tid & 63;
  const int wv   = tid >> 6;                  // 0..3
  const int wr   = wv >> 1;                   // 0..1 (M)
  const int wc   = wv & 1;                    // 0..1 (N)
  const int l15  = lane & 15;
  const int l4   = lane >> 4;

  // XCD chunk (344 = 8*43 exact), by-innermost: A-band sharers on one XCD
  int wgid = blockIdx.x;
  if ((gridDim.x & 7) == 0) {
    const int q = gridDim.x >> 3;
    wgid = (blockIdx.x & 7) * q + (blockIdx.x >> 3);
  }
  const int bx = wgid / gy;
  const int by = wgid % gy;
  const int tileM = by * TM;
  const int tileN = bx * TN;
  const int nT = K / TK;                      // 32 (== NG, since GS == TK)

  // preload scale panel transposed [g][col], folded x-scale 1/16
  for (int idx = tid; idx < NG * 128; idx += 256) {
    const int g = idx >> 7, col = idx & 127;
    sS[g * 128 + col] = scales[(size_t)(tileN + col) * NG + g] * 0.0625f;
  }
  __syncthreads();                            // drains vmcnt: clean queue

  const int8_t* srcA = wsA + (size_t)by * nT * 16384;
  const int8_t* srcB = wsB + (size_t)bx * nT * 16384;

  i32x4 acc[4][4];
  f32x4 accf[4][4];
#pragma unroll
  for (int m = 0; m < 4; ++m)
#pragma unroll
    for (int n = 0; n < 4; ++n) { acc[m][n] = (i32x4)0; accf[m][n] = (f32x4)0.0f; }

  // 8 gload_lds16 per thread per stage (A 4 + B 4); 16 KB each operand
  auto STAGE = [&](int buf, int t) {
    const int8_t* a = srcA + (size_t)t * 16384;
    const int8_t* b = srcB + (size_t)t * 16384;
#pragma unroll
    for (int i = 0; i < 4; ++i) {
      const int ub = i * 256 + wv * 64;       // uniform unit base; +lane per lane
      gload_lds16(a + (size_t)(ub + lane) * 16, &As[buf][ub * 16]);
      gload_lds16(b + (size_t)(ub + lane) * 16, &Bs[buf][ub * 16]);
    }
  };

  STAGE(0, 0);
  STAGE(1, 1);                                // 16 outstanding per thread

  for (int t = 0; t < nT; ++t) {
    if (t + 1 < nT) { asm volatile("s_waitcnt vmcnt(8)" ::: "memory"); }
    else            { asm volatile("s_waitcnt vmcnt(0)" ::: "memory"); }
    __builtin_amdgcn_s_barrier();
    __builtin_amdgcn_sched_barrier(0);

    const int cur = t & 1;
#pragma unroll
    for (int kk = 0; kk < 2; ++kk) {          // two K=64 MFMAs per 128-k tile
      const int c16 = kk * 4 + l4;
      i32x4 af[4], bf[4];
#pragma unroll
      for (int m = 0; m < 4; ++m) {
        const int row = wr * 64 + m * 16 + l15;
        const int sl = c16 ^ (row & 7);
        af[m] = *reinterpret_cast<const i32x4*>(&As[cur][row * 128 + sl * 16]);
      }
#pragma unroll
      for (int n = 0; n < 4; ++n) {
        const int col = wc * 64 + n * 16 + l15;
        const int sl = c16 ^ (col & 7);
        bf[n] = *reinterpret_cast<const i32x4*>(&Bs[cur][col * 128 + sl * 16]);
      }
#pragma unroll
      for (int m = 0; m < 4; ++m)
#pragma unroll
        for (int n = 0; n < 4; ++n)
          acc[m][n] = __builtin_amdgcn_mfma_i32_16x16x64_i8(af[m], bf[n], acc[m][n], 0, 0, 0);
    }

    __builtin_amdgcn_sched_barrier(0);
    __builtin_amdgcn_s_barrier();             // buf cur consumed by all waves
    if (t + 2 < nT) STAGE(cur, t + 2);

    // group close (g == t, GS == TK): accf += s[col] * float(acc); acc = 0
    float s[4];
#pragma unroll
    for (int n = 0; n < 4; ++n)
      s[n] = sS[t * 128 + wc * 64 + n * 16 + l15];
#pragma unroll
    for (int m = 0; m < 4; ++m)
#pragma unroll
      for (int n = 0; n < 4; ++n) {
        accf[m][n] += s[n] * __builtin_convertvector(acc[m][n], f32x4);
        acc[m][n] = (i32x4)0;
      }
    __builtin_amdgcn_sched_barrier(0);
  }

  // epilogue: D row = l4*4 + r, col = l15 (verified, dtype-independent)
#pragma unroll
  for (int n = 0; n < 4; ++n) {
    const int col = tileN + wc * 64 + n * 16 + l15;
    const float bv = bias[col];
#pragma unroll
    for (int m = 0; m < 4; ++m) {
      const int rbase = tileM + wr * 64 + m * 16 + l4 * 4;
#pragma unroll
      for (int r = 0; r < 4; ++r)
        out[(size_t)(rbase + r) * N + col] = accf[m][n][r] + bv;
    }
  }
}

// ======================= last-resort fallback (no ws) =======================
#define FBM 128
#define FBN 128
#define FBK 64
__global__ __launch_bounds__(256)
void gptq_gemm_fb(const float* __restrict__ x, const int* __restrict__ qw,
                  const float* __restrict__ scales, const float* __restrict__ bias,
                  float* __restrict__ out, int M, int N, int K, int NG, int GS) {
  __shared__ __bf16 lds_a[FBM * FBK];
  __shared__ __bf16 lds_b[FBN * FBK];
  const int tid = threadIdx.x, lane = tid & 63, wave = tid >> 6;
  const int wr = wave >> 1, wc = wave & 1;
  const int tileM = blockIdx.y * FBM, tileN = blockIdx.x * FBN;
  const int l15 = lane & 15, l4 = lane >> 4;
  f32x4 acc[4][4];
#pragma unroll
  for (int m = 0; m < 4; ++m)
#pragma unroll
    for (int n = 0; n < 4; ++n) acc[m][n] = (f32x4)0.0f;
  for (int k0 = 0; k0 < K; k0 += FBK) {
    const int g = k0 / GS;
#pragma unroll
    for (int i = 0; i < 4; ++i) {
      int u = i * 256 + tid, row = u >> 3, c8 = u & 7;
      const f32x4* src = reinterpret_cast<const f32x4*>(x + (size_t)(tileM + row) * K + k0 + c8 * 8);
      f32x4 v0 = src[0], v1 = src[1];
      bf16x8 w;
      w[0]=(__bf16)v0[0]; w[1]=(__bf16)v0[1]; w[2]=(__bf16)v0[2]; w[3]=(__bf16)v0[3];
      w[4]=(__bf16)v1[0]; w[5]=(__bf16)v1[1]; w[6]=(__bf16)v1[2]; w[7]=(__bf16)v1[3];
      int slot = c8 ^ (row & 7);
      *reinterpret_cast<bf16x8*>(&lds_a[row * FBK + slot * 8]) = w;
    }
#pragma unroll
    for (int i = 0; i < 4; ++i) {
      int u = i * 256 + tid, row = u >> 3, c8 = u & 7;
      int gn = tileN + row;
      const i32x4* src = reinterpret_cast<const i32x4*>(qw + (size_t)gn * K + k0 + c8 * 8);
      i32x4 q0 = src[0], q1 = src[1];
      float s = scales[gn * NG + g];
      bf16x8 w;
      w[0]=(__bf16)((float)q0[0]*s); w[1]=(__bf16)((float)q0[1]*s);
      w[2]=(__bf16)((float)q0[2]*s); w[3]=(__bf16)((float)q0[3]*s);
      w[4]=(__bf16)((float)q1[0]*s); w[5]=(__bf16)((float)q1[1]*s);
      w[6]=(__bf16)((float)q1[2]*s); w[7]=(__bf16)((float)q1[3]*s);
      int slot = c8 ^ (row & 7);
      *reinterpret_cast<bf16x8*>(&lds_b[row * FBK + slot * 8]) = w;
    }
    __syncthreads();
#pragma unroll
    for (int kk = 0; kk < FBK; kk += 32) {
      bf16x8 af[4], bfr[4];
#pragma unroll
      for (int m = 0; m < 4; ++m) {
        int row = wr * 64 + m * 16 + l15, slot = ((kk >> 3) + l4) ^ (row & 7);
        af[m] = *reinterpret_cast<const bf16x8*>(&lds_a[row * FBK + slot * 8]);
      }
#pragma unroll
      for (int n = 0; n < 4; ++n) {
        int row = wc * 64 + n * 16 + l15, slot = ((kk >> 3) + l4) ^ (row & 7);
        bfr[n] = *reinterpret_cast<const bf16x8*>(&lds_b[row * FBK + slot * 8]);
      }
#pragma unroll
      for (int m = 0; m < 4; ++m)
#pragma unroll
        for (int n = 0; n < 4; ++n)
          acc[m][n] = __builtin_amdgcn_mfma_f32_16x16x32_bf16(af[m], bfr[n], acc[m][n], 0, 0, 0);
    }
    __syncthreads();
  }
#pragma unroll
  for (int n = 0; n < 4; ++n) {
    int coln = tileN + wc * 64 + n * 16 + l15;
    float bv = bias[coln];
#pragma unroll
    for (int m = 0; m < 4; ++m) {
      int rbase = tileM + wr * 64 + m * 16 + l4 * 4;
#pragma unroll
      for (int r = 0; r < 4; ++r)
        out[(size_t)(rbase + r) * N + coln] = acc[m][n][r] + bv;
    }
  }
}

extern "C" void kernel_launch(void* const* d_in, const int* in_sizes, int n_in,
                              void* d_out, int out_size, void* d_ws, size_t ws_size,
                              hipStream_t stream) {
  const float* x      = (const float*)d_in[0];
  const int*   qw     = (const int*)d_in[1];
  const float* scales = (const float*)d_in[2];
  const float* bias   = (const float*)d_in[3];
  float*       out    = (float*)d_out;

  const int OUT = in_sizes[3];            // 11008
  const int IN  = in_sizes[1] / OUT;      // 4096
  const int M   = in_sizes[0] / IN;       // 512
  const int NG  = in_sizes[2] / OUT;      // 32
  const int GS  = IN / NG;                // 128

  const size_t needB = (size_t)OUT * IN;              // 45.1 MB int8
  const size_t needA = (size_t)M * IN;                // 2.1 MB int8
  const int nT = IN / TK;                             // 32

  const bool ok_i8 =
      (ws_size >= needB + needA) && (M % TM == 0) && (OUT % TN == 0) &&
      (IN % TK == 0) && (GS == TK) && (NG == nT) && (NG <= 32) && (nT >= 4) &&
      (OUT % PROWS == 0) && (IN % 16 == 0);

  if (ok_i8) {
    int8_t* wsB = (int8_t*)d_ws;
    int8_t* wsA = (int8_t*)d_ws + needB;
    pack_rows_i8<<<OUT / PROWS, 256, 0, stream>>>(qw, wsB, IN, nT);
    const int bands = M / 128;            // 4
    const int unitsA = bands * nT * 1024;
    xcvt_i8<<<unitsA / 256, 256, 0, stream>>>(x, wsA, IN, nT);
    const int gx = OUT / TN;              // 86
    const int gy = M / TM;                // 4
    gemm_i8<<<gx * gy, 256, 0, stream>>>(wsA, wsB, scales, bias, out, OUT, IN, NG, gy);
  } else {
    dim3 grid(OUT / FBN, M / FBM);
    gptq_gemm_fb<<<grid, 256, 0, stream>>>(x, qw, scales, bias, out, M, OUT, IN, NG, GS);
  }
}